// Round 1
// baseline (205.756 us; speedup 1.0000x reference)
//
#include <hip/hip_runtime.h>
#include <math.h>

#define TOPK 13
#define PI_F 3.14159265358979323846f

typedef unsigned int u32;
typedef unsigned long long u64;

// monotone float -> uint mapping matching XLA total order (-NaN < -Inf < ... < -0 < +0 < ... < +Inf < NaN)
__device__ __forceinline__ u32 ford(float f) {
    u32 u = __float_as_uint(f);
    return (u & 0x80000000u) ? ~u : (u | 0x80000000u);
}
__device__ __forceinline__ float funord(u32 o) {
    u32 u = (o & 0x80000000u) ? (o & 0x7FFFFFFFu) : ~o;
    return __uint_as_float(u);
}

__device__ __forceinline__ float iou_fn(float4 g, float4 p) {
    float ltx = fmaxf(g.x, p.x), lty = fmaxf(g.y, p.y);
    float rbx = fminf(g.z, p.z), rby = fminf(g.w, p.w);
    float inter = fmaxf(rbx - ltx, 0.0f) * fmaxf(rby - lty, 0.0f);
    float a1 = fmaxf(g.z - g.x, 0.0f) * fmaxf(g.w - g.y, 0.0f);
    float a2 = fmaxf(p.z - p.x, 0.0f) * fmaxf(p.w - p.y, 0.0f);
    return inter / (((a1 + a2) - inter) + 1e-9f);
}

struct RowParams { float av, bar, offc, mx, mn; };

__device__ __forceinline__ RowParams row_params(float4 g) {
    float w = g.z - g.x, h = g.w - g.y;
    float ar = w / (h + 1e-5f);
    float ia = 1.0f / ar;
    RowParams rp;
    rp.av = ia / (2.0f - ia);
    rp.bar = 2.0f / ar;
    rp.offc = PI_F * (1.0f - 2.0f / (2.0f * ar));
    rp.mx = 0.5f + 0.5f * cosf(rp.offc);                                  // cos_fn(0, ar)
    rp.mn = 0.5f + 0.5f * cosf(rp.bar * 90.0f / 180.0f * PI_F + rp.offc); // cos_fn(90, ar)
    return rp;
}

__device__ __forceinline__ float ang_measure(const RowParams& rp, float theta) {
    float cfv = 0.5f + 0.5f * cosf(rp.bar * theta / 180.0f * PI_F + rp.offc);
    float r = (cfv - rp.mn) / (rp.mx - rp.mn) * (1.0f - rp.av) + rp.av;
    return isnan(r) ? 0.0f : r;
}

// align in exact reference op order: (s**1 * iou**5) * ang**3, left-assoc
__device__ __forceinline__ float align_fn(float s, float iou, float r) {
    float iou2 = iou * iou;
    float iou5 = (iou2 * iou2) * iou;
    float r3 = (r * r) * r;
    return (s * iou5) * r3;
}

__global__ void k0_init(int* cnt, int* assign1, u32* pam, u32* pov, int BA, int BN) {
    int t = blockIdx.x * blockDim.x + threadIdx.x;
    if (t < BA) { cnt[t] = 0; assign1[t] = -1; }
    if (t < BN) { pam[t] = 0x80000000u; pov[t] = 0x80000000u; } // ord(+0.0f)
}

__global__ __launch_bounds__(256)
void k1_topk(const float* __restrict__ scores, const float* __restrict__ pbox,
             const float* __restrict__ pang, const float* __restrict__ anc,
             const int* __restrict__ glab, const float* __restrict__ gbox,
             const float* __restrict__ gang, const float* __restrict__ mgt,
             int* __restrict__ cnt, int* __restrict__ assign1,
             int A, int n, int C) {
    int bi = blockIdx.x;
    int b = bi / n;
    int i = bi - b * n;
    int tid = threadIdx.x;

    float mg = mgt[bi];
    float4 g = ((const float4*)gbox)[bi];
    int lab = glab[bi];
    float ga = gang[bi];
    RowParams rp = row_params(g);

    const float4* pb = ((const float4*)pbox) + (size_t)b * A;
    const float* pa = pang + (size_t)b * A;
    const float2* ac = (const float2*)anc;
    const float* sc = scores + (size_t)b * A * C + lab;

    u64 arr[TOPK];
#pragma unroll
    for (int j = 0; j < TOPK; j++) arr[j] = 0ull;

    for (int a = tid; a < A; a += 256) {
        float4 p = pb[a];
        float iou = iou_fn(g, p);
        float th = fabsf(ga - pa[a]);
        float r = ang_measure(rp, th);
        float s = sc[(size_t)a * C];
        float align = align_fn(s, iou, r);
        float2 apt = ac[a];
        float mnv = fminf(fminf(apt.x - g.x, apt.y - g.y), fminf(g.z - apt.x, g.w - apt.y));
        float ing = (mnv > 1e-9f) ? 1.0f : 0.0f;
        float v = align * ing;  // preserves signed zero like the reference multiply
        u64 key = ((u64)ford(v) << 32) | (u64)(0xFFFFFFFFu - (u32)a);
        // static-index sorted insert (desc), no scratch
#pragma unroll
        for (int j = 0; j < TOPK; j++) {
            u64 hi = arr[j] > key ? arr[j] : key;
            u64 lo = arr[j] > key ? key : arr[j];
            arr[j] = hi;
            key = lo;
        }
    }

    __shared__ u64 sh[256];
    for (int round = 0; round < TOPK; round++) {
        u64 head = arr[0];
        sh[tid] = head;
        __syncthreads();
        for (int st = 128; st > 0; st >>= 1) {
            if (tid < st) { u64 o = sh[tid + st]; if (o > sh[tid]) sh[tid] = o; }
            __syncthreads();
        }
        u64 win = sh[0];
        __syncthreads();
        if (head == win && win != 0ull) {  // unique key (index embedded) -> exactly one winner
#pragma unroll
            for (int j = 0; j < TOPK - 1; j++) arr[j] = arr[j + 1];
            arr[TOPK - 1] = 0ull;
            int a = (int)(0xFFFFFFFFu - (u32)(win & 0xFFFFFFFFull));
            if (mg > 0.0f) {
                float2 apt = ac[a];
                float mnv = fminf(fminf(apt.x - g.x, apt.y - g.y), fminf(g.z - apt.x, g.w - apt.y));
                if (mnv > 1e-9f) {  // mask_pos = mask_topk * in_gts * mask_gt
                    atomicAdd(&cnt[(size_t)b * A + a], 1);
                    atomicMax(&assign1[(size_t)b * A + a], i);
                }
            }
        }
    }
}

__global__ __launch_bounds__(256)
void k2_resolve(const float* __restrict__ scores, const float* __restrict__ pbox,
                const float* __restrict__ pang, const int* __restrict__ glab,
                const float* __restrict__ gbox, const float* __restrict__ gang,
                const int* __restrict__ cnt, const int* __restrict__ assign1,
                int* __restrict__ assign, float* __restrict__ alignv,
                u32* __restrict__ pam, u32* __restrict__ pov,
                int bs, int A, int n, int C) {
    int t = blockIdx.x * blockDim.x + threadIdx.x;
    if (t >= bs * A) return;
    int b = t / A;
    int a = t - b * A;
    int c = cnt[t];
    int asg = -1;
    float alv = 0.0f;
    if (c > 0) {
        float4 p = ((const float4*)pbox)[t];
        if (c == 1) {
            asg = assign1[t];
        } else {
            // reference: overlaps.argmax(1) over ALL gt rows, first-max tie-break
            float best = -1.0f;
            asg = 0;
            for (int i = 0; i < n; i++) {
                float4 gi = ((const float4*)gbox)[b * n + i];
                float io = iou_fn(gi, p);
                if (io > best) { best = io; asg = i; }
            }
        }
        float4 g = ((const float4*)gbox)[b * n + asg];
        RowParams rp = row_params(g);
        float iou = iou_fn(g, p);
        float th = fabsf(gang[b * n + asg] - pang[t]);
        float r = ang_measure(rp, th);
        float s = scores[(size_t)t * C + glab[b * n + asg]];
        alv = align_fn(s, iou, r);
        atomicMax(&pam[b * n + asg], ford(alv));
        atomicMax(&pov[b * n + asg], ford(iou));
    }
    assign[t] = asg;
    alignv[t] = alv;
}

__global__ __launch_bounds__(256)
void k3_scalar(const int* __restrict__ glab, const float* __restrict__ gbox,
               const float* __restrict__ gang, const int* __restrict__ assign,
               const float* __restrict__ alignv, const u32* __restrict__ pam,
               const u32* __restrict__ pov, float* __restrict__ out,
               float* __restrict__ normv, int* __restrict__ labfg,
               int bs, int A, int n, int C) {
    int t = blockIdx.x * blockDim.x + threadIdx.x;
    if (t >= bs * A) return;
    int b = t / A;
    int asg = assign[t];
    bool fg = asg >= 0;
    int tgt = fg ? asg : 0;  // argmax of all-zero column is 0 -> gathers gt row 0
    int lb = glab[b * n + tgt];
    if (lb < 0) lb = 0;

    size_t BA = (size_t)bs * A;
    float* o_tlab = out;
    float* o_tbb = out + BA;
    float* o_tang = out + BA * 5;
    float* o_fg = out + BA * 6 + BA * (size_t)C;

    o_tlab[t] = (float)lb;
    ((float4*)o_tbb)[t] = ((const float4*)gbox)[b * n + tgt];
    o_tang[t] = gang[b * n + tgt];
    o_fg[t] = fg ? 1.0f : 0.0f;

    float nv = 0.0f;
    if (fg) {
        float pamv = funord(pam[b * n + asg]);
        float povv = funord(pov[b * n + asg]);
        float vv = (alignv[t] * povv) / (pamv + 1e-9f);
        nv = fmaxf(vv, 0.0f);  // max over i: 59 other rows contribute exactly 0
    }
    normv[t] = nv;
    labfg[t] = fg ? lb : -1;
}

__global__ __launch_bounds__(256)
void k4_ts(const float* __restrict__ normv, const int* __restrict__ labfg,
           float* __restrict__ out, int bs, int A, int C) {
    int Q = C / 4;  // 20
    size_t total = (size_t)bs * A * Q;
    size_t id = (size_t)blockIdx.x * blockDim.x + threadIdx.x;
    if (id >= total) return;
    int t = (int)(id / Q);
    int q = (int)(id - (size_t)t * Q);
    float nv = normv[t];
    int lf = labfg[t];
    int cb = q * 4;
    float4 o;
    o.x = (lf == cb) ? nv : 0.0f;
    o.y = (lf == cb + 1) ? nv : 0.0f;
    o.z = (lf == cb + 2) ? nv : 0.0f;
    o.w = (lf == cb + 3) ? nv : 0.0f;
    float* o_ts = out + (size_t)bs * A * 6;
    ((float4*)o_ts)[id] = o;
}

extern "C" void kernel_launch(void* const* d_in, const int* in_sizes, int n_in,
                              void* d_out, int out_size, void* d_ws, size_t ws_size,
                              hipStream_t stream) {
    const float* scores = (const float*)d_in[0];
    const float* pbox = (const float*)d_in[1];
    const float* pang = (const float*)d_in[2];
    const float* anc = (const float*)d_in[3];
    const int* glab = (const int*)d_in[4];
    const float* gbox = (const float*)d_in[5];
    const float* gang = (const float*)d_in[6];
    const float* mgt = (const float*)d_in[7];

    const int C = 80;
    int A = in_sizes[3] / 2;
    int bs = in_sizes[0] / (A * C);
    int n = in_sizes[4] / bs;
    int BA = bs * A;
    int BN = bs * n;

    char* ws = (char*)d_ws;
    int* cnt = (int*)ws;        ws += sizeof(int) * (size_t)BA;
    int* assign1 = (int*)ws;    ws += sizeof(int) * (size_t)BA;
    int* assign = (int*)ws;     ws += sizeof(int) * (size_t)BA;
    float* alignv = (float*)ws; ws += sizeof(float) * (size_t)BA;
    float* normv = (float*)ws;  ws += sizeof(float) * (size_t)BA;
    int* labfg = (int*)ws;      ws += sizeof(int) * (size_t)BA;
    u32* pam = (u32*)ws;        ws += sizeof(u32) * (size_t)BN;
    u32* pov = (u32*)ws;        ws += sizeof(u32) * (size_t)BN;

    k0_init<<<(BA + 255) / 256, 256, 0, stream>>>(cnt, assign1, pam, pov, BA, BN);
    k1_topk<<<BN, 256, 0, stream>>>(scores, pbox, pang, anc, glab, gbox, gang, mgt,
                                    cnt, assign1, A, n, C);
    k2_resolve<<<(BA + 255) / 256, 256, 0, stream>>>(scores, pbox, pang, glab, gbox, gang,
                                                     cnt, assign1, assign, alignv, pam, pov,
                                                     bs, A, n, C);
    k3_scalar<<<(BA + 255) / 256, 256, 0, stream>>>(glab, gbox, gang, assign, alignv, pam, pov,
                                                    (float*)d_out, normv, labfg, bs, A, n, C);
    int Q = C / 4;
    size_t tsThreads = (size_t)BA * Q;
    k4_ts<<<(int)((tsThreads + 255) / 256), 256, 0, stream>>>(normv, labfg, (float*)d_out, bs, A, C);
}

// Round 3
// 171.920 us; speedup vs baseline: 1.1968x; 1.1968x over previous
//
#include <hip/hip_runtime.h>
#include <math.h>

#define TOPK 13
#define PI_F 3.14159265358979323846f

typedef unsigned int u32;
typedef unsigned long long u64;

// monotone float -> uint mapping matching XLA total order
__device__ __forceinline__ u32 ford(float f) {
    u32 u = __float_as_uint(f);
    return (u & 0x80000000u) ? ~u : (u | 0x80000000u);
}
__device__ __forceinline__ float funord(u32 o) {
    u32 u = (o & 0x80000000u) ? (o & 0x7FFFFFFFu) : ~o;
    return __uint_as_float(u);
}

__device__ __forceinline__ float iou_fn(float4 g, float4 p) {
    float ltx = fmaxf(g.x, p.x), lty = fmaxf(g.y, p.y);
    float rbx = fminf(g.z, p.z), rby = fminf(g.w, p.w);
    float inter = fmaxf(rbx - ltx, 0.0f) * fmaxf(rby - lty, 0.0f);
    float a1 = fmaxf(g.z - g.x, 0.0f) * fmaxf(g.w - g.y, 0.0f);
    float a2 = fmaxf(p.z - p.x, 0.0f) * fmaxf(p.w - p.y, 0.0f);
    return inter / (((a1 + a2) - inter) + 1e-9f);
}

struct RowParams { float av, bar, offc, mx, mn; };

__device__ __forceinline__ RowParams row_params(float4 g) {
    float w = g.z - g.x, h = g.w - g.y;
    float ar = w / (h + 1e-5f);
    float ia = 1.0f / ar;
    RowParams rp;
    rp.av = ia / (2.0f - ia);
    rp.bar = 2.0f / ar;
    rp.offc = PI_F * (1.0f - 2.0f / (2.0f * ar));
    rp.mx = 0.5f + 0.5f * cosf(rp.offc);
    rp.mn = 0.5f + 0.5f * cosf(rp.bar * 90.0f / 180.0f * PI_F + rp.offc);
    return rp;
}

__device__ __forceinline__ float ang_measure(const RowParams& rp, float theta) {
    float cfv = 0.5f + 0.5f * cosf(rp.bar * theta / 180.0f * PI_F + rp.offc);
    float r = (cfv - rp.mn) / (rp.mx - rp.mn) * (1.0f - rp.av) + rp.av;
    return isnan(r) ? 0.0f : r;
}

// align in exact reference op order: (s**1 * iou**5) * ang**3, left-assoc
__device__ __forceinline__ float align_fn(float s, float iou, float r) {
    float iou2 = iou * iou;
    float iou5 = (iou2 * iou2) * iou;
    float r3 = (r * r) * r;
    return (s * iou5) * r3;
}

__global__ void k0_init(int* cnt, int* assign1, u32* pam, u32* pov, int BA, int BN) {
    int t = blockIdx.x * blockDim.x + threadIdx.x;
    if (t < BA) { cnt[t] = 0; assign1[t] = -1; }
    if (t < BN) { pam[t] = 0x80000000u; pov[t] = 0x80000000u; } // ord(+0.0f)
}

__global__ __launch_bounds__(256)
void k1_topk(const float* __restrict__ scores, const float* __restrict__ pbox,
             const float* __restrict__ pang, const float* __restrict__ anc,
             const int* __restrict__ glab, const float* __restrict__ gbox,
             const float* __restrict__ gang, const float* __restrict__ mgt,
             int* __restrict__ cnt, int* __restrict__ assign1,
             int bs, int A, int n, int C) {
    int j = blockIdx.x;
    // XCD clustering: blocks of the same batch land on the same XCD (j % 8 == b % 8)
    int b = j % bs;
    int i = j / bs;
    int bi = b * n + i;
    int tid = threadIdx.x;

    float mg = mgt[bi];
    if (!(mg > 0.0f)) return;   // masked row: reference wipes it (cnt>1 at idx0 / mask mult)

    float4 g = ((const float4*)gbox)[bi];
    int lab = glab[bi];
    float ga = gang[bi];
    RowParams rp = row_params(g);

    const float4* pb = ((const float4*)pbox) + (size_t)b * A;
    const float* pa = pang + (size_t)b * A;
    const float2* ac = (const float2*)anc;
    const float* sc = scores + (size_t)b * A * C + lab;

    u64 arr[TOPK];
#pragma unroll
    for (int jj = 0; jj < TOPK; jj++) arr[jj] = 0ull;
    u64 zkey = 0ull;  // thread's lowest-index exact-+0 candidate

    for (int a = tid; a < A; a += 256) {
        float4 p = pb[a];
        float iou = iou_fn(g, p);
        float2 apt = ac[a];
        float mnv = fminf(fminf(apt.x - g.x, apt.y - g.y), fminf(g.z - apt.x, g.w - apt.y));
        bool inGt = mnv > 1e-9f;
        float th = fabsf(ga - pa[a]);
        float r = ang_measure(rp, th);

        // Reference v = align * in_gts, align = (s*iou^5)*r^3, s>0, iou>=0.
        // Classes: v>0 (positive, needs s); v==+0 (zero candidate, ranked by index);
        // v<0 or v==-0 (never selectable: >=8100 +0 zeros per row always exist).
        // sign(v) for non-positive cases == sign(r) (s>0, iou^5>=+0).
        bool zeroCand;
        if (inGt && iou > 0.0f && r > 0.0f) {
            float s = sc[(size_t)a * C];   // scattered load, rare path only
            float v = align_fn(s, iou, r);
            if (v > 0.0f) {
                zeroCand = false;
                u64 key = ((u64)ford(v) << 32) | (u64)(0xFFFFFFFFu - (u32)a);
                if (key > arr[TOPK - 1]) {
#pragma unroll
                    for (int jj = 0; jj < TOPK; jj++) {
                        u64 hi = arr[jj] > key ? arr[jj] : key;
                        u64 lo = arr[jj] > key ? key : arr[jj];
                        arr[jj] = hi;
                        key = lo;
                    }
                }
            } else {
                zeroCand = true;  // s==0 or iou^5 underflow -> v == +0 exactly
            }
        } else {
            zeroCand = (r >= 0.0f);  // v == sign(r)*0; only +0 is selectable
        }
        if (zeroCand && zkey == 0ull) {
            zkey = (0x80000000ull << 32) | (u64)(0xFFFFFFFFu - (u32)a);
        }
    }
    // merge the single zero candidate (provably sufficient per thread)
    if (zkey > arr[TOPK - 1]) {
        u64 key = zkey;
#pragma unroll
        for (int jj = 0; jj < TOPK; jj++) {
            u64 hi = arr[jj] > key ? arr[jj] : key;
            u64 lo = arr[jj] > key ? key : arr[jj];
            arr[jj] = hi;
            key = lo;
        }
    }

    // 13 rounds of block-wide max; wave shuffle + 4-slot LDS, double-buffered
    __shared__ u64 sh[2][4];
    int lane = tid & 63, wv = tid >> 6;
    for (int round = 0; round < TOPK; round++) {
        u64 head = arr[0];
        u64 m = head;
#pragma unroll
        for (int st = 32; st > 0; st >>= 1) {
            u64 o = __shfl_xor(m, st, 64);
            if (o > m) m = o;
        }
        if (lane == 0) sh[round & 1][wv] = m;
        __syncthreads();
        u64 win = sh[round & 1][0];
        u64 w1 = sh[round & 1][1]; if (w1 > win) win = w1;
        u64 w2 = sh[round & 1][2]; if (w2 > win) win = w2;
        u64 w3 = sh[round & 1][3]; if (w3 > win) win = w3;
        if (head == win && win != 0ull) {  // unique key (index embedded) -> one winner
#pragma unroll
            for (int jj = 0; jj < TOPK - 1; jj++) arr[jj] = arr[jj + 1];
            arr[TOPK - 1] = 0ull;
            int a = (int)(0xFFFFFFFFu - (u32)(win & 0xFFFFFFFFull));
            float2 apt = ac[a];
            float mnv = fminf(fminf(apt.x - g.x, apt.y - g.y), fminf(g.z - apt.x, g.w - apt.y));
            if (mnv > 1e-9f) {  // mask_pos = mask_topk * in_gts * mask_gt
                atomicAdd(&cnt[(size_t)b * A + a], 1);
                atomicMax(&assign1[(size_t)b * A + a], i);
            }
        }
    }
}

__global__ __launch_bounds__(256)
void k2_resolve(const float* __restrict__ scores, const float* __restrict__ pbox,
                const float* __restrict__ pang, const int* __restrict__ glab,
                const float* __restrict__ gbox, const float* __restrict__ gang,
                const int* __restrict__ cnt, const int* __restrict__ assign1,
                int* __restrict__ assign, float* __restrict__ alignv,
                u32* __restrict__ pam, u32* __restrict__ pov,
                int bs, int A, int n, int C) {
    int t = blockIdx.x * blockDim.x + threadIdx.x;
    if (t >= bs * A) return;
    int b = t / A;
    int c = cnt[t];
    int asg = -1;
    float alv = 0.0f;
    if (c > 0) {
        float4 p = ((const float4*)pbox)[t];
        if (c == 1) {
            asg = assign1[t];
        } else {
            // reference: overlaps.argmax(1) over ALL gt rows, first-max tie-break
            float best = -1.0f;
            asg = 0;
            for (int i = 0; i < n; i++) {
                float4 gi = ((const float4*)gbox)[b * n + i];
                float io = iou_fn(gi, p);
                if (io > best) { best = io; asg = i; }
            }
        }
        float4 g = ((const float4*)gbox)[b * n + asg];
        RowParams rp = row_params(g);
        float iou = iou_fn(g, p);
        float th = fabsf(gang[b * n + asg] - pang[t]);
        float r = ang_measure(rp, th);
        float s = scores[(size_t)t * C + glab[b * n + asg]];
        alv = align_fn(s, iou, r);
        atomicMax(&pam[b * n + asg], ford(alv));
        atomicMax(&pov[b * n + asg], ford(iou));
    }
    assign[t] = asg;
    alignv[t] = alv;
}

__global__ __launch_bounds__(256)
void k3_out(const int* __restrict__ glab, const float* __restrict__ gbox,
            const float* __restrict__ gang, const int* __restrict__ assign,
            const float* __restrict__ alignv, const u32* __restrict__ pam,
            const u32* __restrict__ pov, float* __restrict__ out,
            int bs, int A, int n, int C) {
    __shared__ float s_nv[256];
    __shared__ int s_lf[256];
    int tid = threadIdx.x;
    int base = blockIdx.x * 256;
    int t = base + tid;
    int BA = bs * A;

    if (t < BA) {
        int b = t / A;
        int asg = assign[t];
        bool fg = asg >= 0;
        int tgt = fg ? asg : 0;  // argmax of all-zero column -> row 0
        int lb = glab[b * n + tgt];
        if (lb < 0) lb = 0;

        float* o_tlab = out;
        float* o_tbb = out + BA;
        float* o_tang = out + (size_t)BA * 5;
        float* o_fg = out + (size_t)BA * 6 + (size_t)BA * C;

        o_tlab[t] = (float)lb;
        ((float4*)o_tbb)[t] = ((const float4*)gbox)[b * n + tgt];
        o_tang[t] = gang[b * n + tgt];
        o_fg[t] = fg ? 1.0f : 0.0f;

        float nv = 0.0f;
        if (fg) {
            float pamv = funord(pam[b * n + asg]);
            float povv = funord(pov[b * n + asg]);
            float vv = (alignv[t] * povv) / (pamv + 1e-9f);
            nv = fmaxf(vv, 0.0f);  // 59 other rows contribute exactly 0 to the max
        }
        s_nv[tid] = nv;
        s_lf[tid] = fg ? lb : -1;
    } else {
        s_nv[tid] = 0.0f;
        s_lf[tid] = -1;
    }
    __syncthreads();

    // ts: coalesced float4 writes, (anchor, class-quad) with quad fastest
    int Q = C / 4;  // 20
    int nA = min(256, BA - base);
    if (nA <= 0) return;
    int total = nA * Q;
    float4* o_ts = (float4*)(out + (size_t)BA * 6) + (size_t)base * Q;
    for (int idx = tid; idx < total; idx += 256) {
        int tl = idx / Q;
        int q = idx - tl * Q;
        float nv = s_nv[tl];
        int lf = s_lf[tl];
        int cb = q * 4;
        float4 o;
        o.x = (lf == cb) ? nv : 0.0f;
        o.y = (lf == cb + 1) ? nv : 0.0f;
        o.z = (lf == cb + 2) ? nv : 0.0f;
        o.w = (lf == cb + 3) ? nv : 0.0f;
        o_ts[idx] = o;
    }
}

extern "C" void kernel_launch(void* const* d_in, const int* in_sizes, int n_in,
                              void* d_out, int out_size, void* d_ws, size_t ws_size,
                              hipStream_t stream) {
    const float* scores = (const float*)d_in[0];
    const float* pbox = (const float*)d_in[1];
    const float* pang = (const float*)d_in[2];
    const float* anc = (const float*)d_in[3];
    const int* glab = (const int*)d_in[4];
    const float* gbox = (const float*)d_in[5];
    const float* gang = (const float*)d_in[6];
    const float* mgt = (const float*)d_in[7];

    const int C = 80;
    int A = in_sizes[3] / 2;
    int bs = in_sizes[0] / (A * C);
    int n = in_sizes[4] / bs;
    int BA = bs * A;
    int BN = bs * n;

    char* ws = (char*)d_ws;
    int* cnt = (int*)ws;        ws += sizeof(int) * (size_t)BA;
    int* assign1 = (int*)ws;    ws += sizeof(int) * (size_t)BA;
    int* assign = (int*)ws;     ws += sizeof(int) * (size_t)BA;
    float* alignv = (float*)ws; ws += sizeof(float) * (size_t)BA;
    u32* pam = (u32*)ws;        ws += sizeof(u32) * (size_t)BN;
    u32* pov = (u32*)ws;        ws += sizeof(u32) * (size_t)BN;

    k0_init<<<(BA + 255) / 256, 256, 0, stream>>>(cnt, assign1, pam, pov, BA, BN);
    k1_topk<<<BN, 256, 0, stream>>>(scores, pbox, pang, anc, glab, gbox, gang, mgt,
                                    cnt, assign1, bs, A, n, C);
    k2_resolve<<<(BA + 255) / 256, 256, 0, stream>>>(scores, pbox, pang, glab, gbox, gang,
                                                     cnt, assign1, assign, alignv, pam, pov,
                                                     bs, A, n, C);
    k3_out<<<(BA + 255) / 256, 256, 0, stream>>>(glab, gbox, gang, assign, alignv, pam, pov,
                                                 (float*)d_out, bs, A, n, C);
}